// Round 19
// baseline (98.472 us; speedup 1.0000x reference)
//
#include <hip/hip_runtime.h>

typedef __attribute__((ext_vector_type(8))) short bf16x8;
typedef __attribute__((ext_vector_type(4))) float f32x4;
typedef unsigned int uint32;
typedef unsigned short u16;

#define BN 1024
// K1 = 3; inputs f32, output f32.

__device__ __align__(16) float g_stats[6 * 8192];          // sir,sii,sjr,sji,M,Z
__device__ __align__(16) u16   g_Xt[8 * 16 * 2 * 64 * 64]; // X^T bf16 [b][q][p][c][j]
__device__ __align__(16) u16   g_wt[6 * 64 * 192];         // w bf16 [plane][o][kc]
__device__ __align__(16) float g_part[2048 * 6144];        // partial LX [tile16xjh][rc2][16][192]

__device__ __forceinline__ u16 f2bf(float x) {
    uint32 u = __float_as_uint(x);
    u += 0x7fffu + ((u >> 16) & 1u);
    return (u16)(u >> 16);
}
__device__ __forceinline__ float bf2f(u16 h) {
    return __uint_as_float(((uint32)h) << 16);
}

// ---------------- K0: si/sj projections ----------------
__global__ void k_sisj(const float* __restrict__ Xr, const float* __restrict__ Xi,
                       const float* __restrict__ asr, const float* __restrict__ asi,
                       const float* __restrict__ adr, const float* __restrict__ adi) {
    int wid = threadIdx.x >> 6, lane = threadIdx.x & 63;
    int bn = blockIdx.x * 4 + wid;
    float xr = Xr[(size_t)bn * 64 + lane], xi = Xi[(size_t)bn * 64 + lane];
    float r0 = asr[lane], i0 = asi[lane], r1 = adr[lane], i1 = adi[lane];
    float v0 = xr * r0 - xi * i0;
    float v1 = xr * i0 + xi * r0;
    float v2 = xr * r1 - xi * i1;
    float v3 = xr * i1 + xi * r1;
    #pragma unroll
    for (int off = 32; off; off >>= 1) {
        v0 += __shfl_xor(v0, off);
        v1 += __shfl_xor(v1, off);
        v2 += __shfl_xor(v2, off);
        v3 += __shfl_xor(v3, off);
    }
    if (lane == 0) {
        g_stats[bn]         = v0;
        g_stats[8192 + bn]  = v1;
        g_stats[16384 + bn] = v2;
        g_stats[24576 + bn] = v3;
    }
}

// ---------------- K1: per-(b,j) softmax stats over i ----------------
__global__ void k_mz(const float* __restrict__ pbr, const float* __restrict__ pbi,
                     const float* __restrict__ par, const float* __restrict__ pai) {
    int wid = threadIdx.x >> 6, lane = threadIdx.x & 63;
    int bj = blockIdx.x * 4 + wid;
    int b = bj >> 10;
    float br = pbr[0], bi = pbi[0], ar = par[0], ai = pai[0];
    float sjrv = g_stats[16384 + bj], sjiv = g_stats[24576 + bj];
    float mags[16];
    float mx = 0.0f;
    #pragma unroll
    for (int t = 0; t < 16; ++t) {
        int i = t * 64 + lane;
        float sr = g_stats[b * BN + i] + sjrv + br;
        float si = g_stats[8192 + b * BN + i] + sjiv + bi;
        sr = sr >= 0.f ? sr : ar * sr;
        si = si >= 0.f ? si : ai * si;
        float m = sqrtf(sr * sr + si * si);
        mags[t] = m;
        mx = fmaxf(mx, m);
    }
    #pragma unroll
    for (int off = 32; off; off >>= 1) mx = fmaxf(mx, __shfl_xor(mx, off));
    float s = 0.f;
    #pragma unroll
    for (int t = 0; t < 16; ++t) s += __expf(mags[t] - mx);
    #pragma unroll
    for (int off = 32; off; off >>= 1) s += __shfl_xor(s, off);
    if (lane == 0) { g_stats[32768 + bj] = mx; g_stats[40960 + bj] = s; }
}

// ---------------- K2a: X -> transposed bf16 g_Xt[b][q][p][c][j] ----------------
__global__ void k_xt(const float* __restrict__ Xr, const float* __restrict__ Xi) {
    int b = blockIdx.x >> 4, q = blockIdx.x & 15;
    __shared__ float xs[2][64][65];
    int tid = threadIdx.x;
    #pragma unroll 4
    for (int rep = 0; rep < 32; ++rep) {
        int idx = rep * 256 + tid;                  // 8192
        int p = idx >> 12, j = (idx >> 6) & 63, c = idx & 63;
        const float* src = p ? Xi : Xr;
        xs[p][j][c] = src[((size_t)b * BN + q * 64 + j) * 64 + c];
    }
    __syncthreads();
    #pragma unroll
    for (int rep = 0; rep < 4; ++rep) {
        int idx = rep * 256 + tid;                  // 1024 uint4
        int p = idx >> 9, c = (idx >> 3) & 63, j8 = idx & 7;
        union { u16 h[8]; uint4 v; } pk;
        #pragma unroll
        for (int jj = 0; jj < 8; ++jj) pk.h[jj] = f2bf(xs[p][j8 * 8 + jj][c]);
        *(uint4*)&g_Xt[(size_t)(((b * 16 + q) * 2 + p) * 64 + c) * 64 + j8 * 8] = pk.v;
    }
}

// ---------------- K2b: w -> bf16 hi/lo planes g_wt[plane][o][kc] ----------------
__global__ void k_wt(const float* __restrict__ wr, const float* __restrict__ wi) {
    int t = blockIdx.x * 256 + threadIdx.x;         // 0..12287 ; w[k][c][o], t = kc*64+o
    int o = t & 63, kc = t >> 6;
    float vr = wr[t], vi = wi[t];
    u16 rh = f2bf(vr);
    u16 rl = f2bf(vr - bf2f(rh));
    u16 ih = f2bf(vi);
    u16 il = f2bf(vi - bf2f(ih));
    g_wt[(0 * 64 + o) * 192 + kc] = rh;
    g_wt[(1 * 64 + o) * 192 + kc] = rl;
    g_wt[(2 * 64 + o) * 192 + kc] = ih;
    g_wt[(3 * 64 + o) * 192 + kc] = il;
    g_wt[(4 * 64 + o) * 192 + kc] = (u16)(ih ^ 0x8000u);
    g_wt[(5 * 64 + o) * 192 + kc] = (u16)(il ^ 0x8000u);
}

// ---------------- K3: main kernel — barrier-free register pipeline ----------------
// grid 512 = b(8) x it4(16 row-tiles of 64) x jh(4); 256 thr = 4 waves.
// Wave w owns rows i0 = it4*64 + w*16; sweeps its jh-quarter (8 K=32 slices);
// accumulates ALL 4 c-quarters and 3 Chebyshev k (96 acc VGPR).
// A-fragments built per-lane in registers (lane: row=l&15, j's=(l>>4)*8..+7).
__global__ __launch_bounds__(256, 2) void k_main(
    const float* __restrict__ Lr, const float* __restrict__ Li,
    const float* __restrict__ pbr, const float* __restrict__ pbi,
    const float* __restrict__ par, const float* __restrict__ pai) {
    __shared__ __align__(16) float stS[4][256];
    __shared__ __align__(16) float sA[2][64];

    int tid = threadIdx.x, w = tid >> 6, lane = tid & 63;
    int jh = blockIdx.x & 3, it4 = (blockIdx.x >> 2) & 15, b = blockIdx.x >> 6;
    int i0 = it4 * 64 + w * 16;
    int arow = lane & 15, kb = (lane >> 4) * 8;

    // stage stats for this jh quarter + si for the block's 64 rows (one barrier total)
    {
        int jg = b * BN + jh * 256 + tid;
        stS[0][tid] = g_stats[16384 + jg];
        stS[1][tid] = g_stats[24576 + jg];
        stS[2][tid] = g_stats[32768 + jg];
        stS[3][tid] = g_stats[40960 + jg];
        if (tid < 128) {
            int p = tid >> 6, i = tid & 63;
            sA[p][i] = g_stats[p * 8192 + b * BN + it4 * 64 + i];
        }
    }
    __syncthreads();

    float brv = pbr[0], biv = pbi[0], alrv = par[0], aliv = pai[0];
    float sirv = sA[0][w * 16 + arow], siiv = sA[1][w * 16 + arow];

    f32x4 zz = {0.f, 0.f, 0.f, 0.f};
    f32x4 accr[3][4], acci[3][4];
    #pragma unroll
    for (int k = 0; k < 3; ++k)
        #pragma unroll
        for (int cq = 0; cq < 4; ++cq) { accr[k][cq] = zz; acci[k][cq] = zz; }

    #pragma unroll 2
    for (int s = 0; s < 8; ++s) {
        int q = jh * 4 + (s >> 1);
        int jin = (s & 1) * 32;
        int jloc = s * 32 + kb;
        // ---- attention for this lane's 8 j's (lane-local; matches A-frag layout) ----
        float arj[8], aij[8];
        #pragma unroll
        for (int e = 0; e < 8; ++e) {
            float sr = sirv + stS[0][jloc + e] + brv;
            float si = siiv + stS[1][jloc + e] + biv;
            sr = sr >= 0.f ? sr : alrv * sr;
            si = si >= 0.f ? si : aliv * si;
            float mg = sqrtf(sr * sr + si * si);
            float sc = __expf(mg - stS[2][jloc + e]) / (stS[3][jloc + e] * fmaxf(mg, 1e-12f));
            arj[e] = sc * sr;
            aij[e] = sc * si;
        }
        // ---- L load + modulate -> A-fragments in registers ----
        bf16x8 aR[3], aI[3];
        #pragma unroll
        for (int k = 0; k < 3; ++k) {
            size_t lb = ((size_t)(b * 3 + k) * BN + (i0 + arow)) * BN + jh * 256 + s * 32 + kb;
            float4 r0 = *(const float4*)&Lr[lb], r1 = *(const float4*)&Lr[lb + 4];
            float4 s0 = *(const float4*)&Li[lb], s1 = *(const float4*)&Li[lb + 4];
            float lr8[8] = {r0.x, r0.y, r0.z, r0.w, r1.x, r1.y, r1.z, r1.w};
            float li8[8] = {s0.x, s0.y, s0.z, s0.w, s1.x, s1.y, s1.z, s1.w};
            union { u16 h[8]; bf16x8 v; } pr, pi;
            #pragma unroll
            for (int e = 0; e < 8; ++e) {
                float mr = lr8[e] * arj[e] - li8[e] * aij[e];
                float mi = lr8[e] * aij[e] + li8[e] * arj[e];
                pr.h[e] = f2bf(mr);
                pi.h[e] = f2bf(mi);
            }
            aR[k] = pr.v;
            aI[k] = pi.v;
        }
        // ---- B-fragments from g_Xt (L2) + MFMA, per c-quarter ----
        size_t xb = (size_t)((b * 16 + q) * 2) * 4096 + (size_t)arow * 64 + jin + kb;
        #pragma unroll
        for (int cq = 0; cq < 4; ++cq) {
            bf16x8 Bxr = *(const bf16x8*)&g_Xt[xb + cq * 1024];
            bf16x8 Bxi = *(const bf16x8*)&g_Xt[xb + 4096 + cq * 1024];
            bf16x8 nBxi;
            #pragma unroll
            for (int z = 0; z < 8; ++z) nBxi[z] = (short)(Bxi[z] ^ (short)0x8000);
            #pragma unroll
            for (int k = 0; k < 3; ++k) {
                accr[k][cq] = __builtin_amdgcn_mfma_f32_16x16x32_bf16(aR[k], Bxr,  accr[k][cq], 0, 0, 0);
                accr[k][cq] = __builtin_amdgcn_mfma_f32_16x16x32_bf16(aI[k], nBxi, accr[k][cq], 0, 0, 0);
                acci[k][cq] = __builtin_amdgcn_mfma_f32_16x16x32_bf16(aR[k], Bxi,  acci[k][cq], 0, 0, 0);
                acci[k][cq] = __builtin_amdgcn_mfma_f32_16x16x32_bf16(aI[k], Bxr,  acci[k][cq], 0, 0, 0);
            }
        }
    }

    // ---- write partial LX (f32): tile16 = it4*4 + w ----
    {
        size_t base = (size_t)(((b * 64 + it4 * 4 + w) * 4) + jh) * 6144;
        #pragma unroll
        for (int k = 0; k < 3; ++k) {
            #pragma unroll
            for (int cq = 0; cq < 4; ++cq) {
                int kc = k * 64 + cq * 16 + arow;
                #pragma unroll
                for (int p = 0; p < 2; ++p) {
                    f32x4 fr = p ? acci[k][cq] : accr[k][cq];
                    #pragma unroll
                    for (int r = 0; r < 4; ++r) {
                        int row = (lane >> 4) * 4 + r;
                        g_part[base + (size_t)(p * 16 + row) * 192 + kc] = fr[r];
                    }
                }
            }
        }
    }
}

// ---------------- K4: combine 4 partials + stage 2 -> out ----------------
__global__ __launch_bounds__(256) void k_out(float* __restrict__ out) {
    __shared__ __align__(16) u16 LXs[12800];   // [plane4][16][200], kc in [0,192)
    int tid = threadIdx.x, wid = tid >> 6, lane = tid & 63;
    int b = blockIdx.x >> 6, it = blockIdx.x & 63, i0 = it * 16;
    size_t p0 = (size_t)((b * 64 + it) * 4) * 6144;

    #pragma unroll
    for (int rep = 0; rep < 6; ++rep) {
        int idx = rep * 256 + tid;                // 1536 float4 per partial
        float4 a0 = *(const float4*)&g_part[p0 + (size_t)idx * 4];
        float4 a1 = *(const float4*)&g_part[p0 + 6144 + (size_t)idx * 4];
        float4 a2 = *(const float4*)&g_part[p0 + 12288 + (size_t)idx * 4];
        float4 a3 = *(const float4*)&g_part[p0 + 18432 + (size_t)idx * 4];
        float s[4] = {a0.x + a1.x + a2.x + a3.x, a0.y + a1.y + a2.y + a3.y,
                      a0.z + a1.z + a2.z + a3.z, a0.w + a1.w + a2.w + a3.w};
        int f0 = idx * 4;
        int rc = f0 / 3072, rem = f0 - rc * 3072;
        int row = rem / 192, kc = rem - row * 192;
        #pragma unroll
        for (int t = 0; t < 4; ++t) {
            float v = s[t];
            u16 hi = f2bf(v);
            u16 lo = f2bf(v - bf2f(hi));
            LXs[((rc * 2 + 0) * 16 + row) * 200 + kc + t] = hi;
            LXs[((rc * 2 + 1) * 16 + row) * 200 + kc + t] = lo;
        }
    }
    __syncthreads();

    f32x4 zz = {0.f, 0.f, 0.f, 0.f};
    f32x4 o_r = zz, o_i = zz;
    int arow = lane & 15, kb = (lane >> 4) * 8;
    int o = wid * 16 + arow;
    #pragma unroll
    for (int ks = 0; ks < 6; ++ks) {
        int kc = ks * 32 + kb;
        bf16x8 Arh = *(const bf16x8*)(LXs + (0 * 16 + arow) * 200 + kc);
        bf16x8 Arl = *(const bf16x8*)(LXs + (1 * 16 + arow) * 200 + kc);
        bf16x8 Aih = *(const bf16x8*)(LXs + (2 * 16 + arow) * 200 + kc);
        bf16x8 Ail = *(const bf16x8*)(LXs + (3 * 16 + arow) * 200 + kc);
        bf16x8 Wrh  = *(const bf16x8*)&g_wt[(0 * 64 + o) * 192 + kc];
        bf16x8 Wrl  = *(const bf16x8*)&g_wt[(1 * 64 + o) * 192 + kc];
        bf16x8 Wih  = *(const bf16x8*)&g_wt[(2 * 64 + o) * 192 + kc];
        bf16x8 Wil  = *(const bf16x8*)&g_wt[(3 * 64 + o) * 192 + kc];
        bf16x8 Wihn = *(const bf16x8*)&g_wt[(4 * 64 + o) * 192 + kc];
        bf16x8 Wiln = *(const bf16x8*)&g_wt[(5 * 64 + o) * 192 + kc];
        o_r = __builtin_amdgcn_mfma_f32_16x16x32_bf16(Arh, Wrh,  o_r, 0, 0, 0);
        o_r = __builtin_amdgcn_mfma_f32_16x16x32_bf16(Arh, Wrl,  o_r, 0, 0, 0);
        o_r = __builtin_amdgcn_mfma_f32_16x16x32_bf16(Arl, Wrh,  o_r, 0, 0, 0);
        o_r = __builtin_amdgcn_mfma_f32_16x16x32_bf16(Aih, Wihn, o_r, 0, 0, 0);
        o_r = __builtin_amdgcn_mfma_f32_16x16x32_bf16(Aih, Wiln, o_r, 0, 0, 0);
        o_r = __builtin_amdgcn_mfma_f32_16x16x32_bf16(Ail, Wihn, o_r, 0, 0, 0);
        o_i = __builtin_amdgcn_mfma_f32_16x16x32_bf16(Arh, Wih,  o_i, 0, 0, 0);
        o_i = __builtin_amdgcn_mfma_f32_16x16x32_bf16(Arh, Wil,  o_i, 0, 0, 0);
        o_i = __builtin_amdgcn_mfma_f32_16x16x32_bf16(Arl, Wih,  o_i, 0, 0, 0);
        o_i = __builtin_amdgcn_mfma_f32_16x16x32_bf16(Aih, Wrh,  o_i, 0, 0, 0);
        o_i = __builtin_amdgcn_mfma_f32_16x16x32_bf16(Aih, Wrl,  o_i, 0, 0, 0);
        o_i = __builtin_amdgcn_mfma_f32_16x16x32_bf16(Ail, Wrh,  o_i, 0, 0, 0);
    }
    #pragma unroll
    for (int r = 0; r < 4; ++r) {
        int i = (lane >> 4) * 4 + r;
        size_t off = ((size_t)b * BN + i0 + i) * 64 + o;
        out[off] = o_r[r];
        out[524288 + off] = o_i[r];
    }
}

extern "C" void kernel_launch(void* const* d_in, const int* in_sizes, int n_in,
                              void* d_out, int out_size, void* d_ws, size_t ws_size,
                              hipStream_t stream) {
    const float* Xr  = (const float*)d_in[0];
    const float* Xi  = (const float*)d_in[1];
    const float* Lr  = (const float*)d_in[2];
    const float* Li  = (const float*)d_in[3];
    const float* asr = (const float*)d_in[4];
    const float* asi = (const float*)d_in[5];
    const float* adr = (const float*)d_in[6];
    const float* adi = (const float*)d_in[7];
    const float* pbr = (const float*)d_in[8];
    const float* pbi = (const float*)d_in[9];
    const float* par = (const float*)d_in[10];
    const float* pai = (const float*)d_in[11];
    const float* wr  = (const float*)d_in[12];
    const float* wi  = (const float*)d_in[13];
    float* out = (float*)d_out;

    k_sisj<<<2048, 256, 0, stream>>>(Xr, Xi, asr, asi, adr, adi);
    k_mz<<<2048, 256, 0, stream>>>(pbr, pbi, par, pai);
    k_xt<<<128, 256, 0, stream>>>(Xr, Xi);
    k_wt<<<48, 256, 0, stream>>>(wr, wi);
    k_main<<<512, 256, 0, stream>>>(Lr, Li, pbr, pbi, par, pai);
    k_out<<<512, 256, 0, stream>>>(out);
}

// Round 20
// 82.228 us; speedup vs baseline: 1.1975x; 1.1975x over previous
//
#include <hip/hip_runtime.h>

typedef __attribute__((ext_vector_type(8))) short bf16x8;
typedef __attribute__((ext_vector_type(4))) float f32x4;
typedef unsigned int uint32;
typedef unsigned short u16;

#define BN 1024
// K1 = 3; inputs f32, output f32.

__device__ __align__(16) float g_stats[6 * 8192];          // sir,sii,sjr,sji,M,Z
__device__ __align__(16) u16   g_Xt[8 * 16 * 2 * 64 * 64]; // X^T bf16 [b][q][p][c][j]
__device__ __align__(16) u16   g_wt[6 * 64 * 192];         // w bf16 [plane][o][kc]
__device__ __align__(16) float g_part[1024 * 6144];        // partial LX [blk][rc2][16][192]

__device__ __forceinline__ u16 f2bf(float x) {
    uint32 u = __float_as_uint(x);
    u += 0x7fffu + ((u >> 16) & 1u);
    return (u16)(u >> 16);
}
__device__ __forceinline__ float bf2f(u16 h) {
    return __uint_as_float(((uint32)h) << 16);
}
__device__ __forceinline__ void gl_lds16(const float* g, float* l) {
    __builtin_amdgcn_global_load_lds(
        (const __attribute__((address_space(1))) uint32*)g,
        (__attribute__((address_space(3))) uint32*)l, 16, 0, 0);
}

// ---------------- K0: si/sj projections ----------------
__global__ void k_sisj(const float* __restrict__ Xr, const float* __restrict__ Xi,
                       const float* __restrict__ asr, const float* __restrict__ asi,
                       const float* __restrict__ adr, const float* __restrict__ adi) {
    int wid = threadIdx.x >> 6, lane = threadIdx.x & 63;
    int bn = blockIdx.x * 4 + wid;
    float xr = Xr[(size_t)bn * 64 + lane], xi = Xi[(size_t)bn * 64 + lane];
    float r0 = asr[lane], i0 = asi[lane], r1 = adr[lane], i1 = adi[lane];
    float v0 = xr * r0 - xi * i0;
    float v1 = xr * i0 + xi * r0;
    float v2 = xr * r1 - xi * i1;
    float v3 = xr * i1 + xi * r1;
    #pragma unroll
    for (int off = 32; off; off >>= 1) {
        v0 += __shfl_xor(v0, off);
        v1 += __shfl_xor(v1, off);
        v2 += __shfl_xor(v2, off);
        v3 += __shfl_xor(v3, off);
    }
    if (lane == 0) {
        g_stats[bn]         = v0;
        g_stats[8192 + bn]  = v1;
        g_stats[16384 + bn] = v2;
        g_stats[24576 + bn] = v3;
    }
}

// ---------------- K1: per-(b,j) softmax stats over i ----------------
__global__ void k_mz(const float* __restrict__ pbr, const float* __restrict__ pbi,
                     const float* __restrict__ par, const float* __restrict__ pai) {
    int wid = threadIdx.x >> 6, lane = threadIdx.x & 63;
    int bj = blockIdx.x * 4 + wid;
    int b = bj >> 10;
    float br = pbr[0], bi = pbi[0], ar = par[0], ai = pai[0];
    float sjrv = g_stats[16384 + bj], sjiv = g_stats[24576 + bj];
    float mags[16];
    float mx = 0.0f;
    #pragma unroll
    for (int t = 0; t < 16; ++t) {
        int i = t * 64 + lane;
        float sr = g_stats[b * BN + i] + sjrv + br;
        float si = g_stats[8192 + b * BN + i] + sjiv + bi;
        sr = sr >= 0.f ? sr : ar * sr;
        si = si >= 0.f ? si : ai * si;
        float m = sqrtf(sr * sr + si * si);
        mags[t] = m;
        mx = fmaxf(mx, m);
    }
    #pragma unroll
    for (int off = 32; off; off >>= 1) mx = fmaxf(mx, __shfl_xor(mx, off));
    float s = 0.f;
    #pragma unroll
    for (int t = 0; t < 16; ++t) s += __expf(mags[t] - mx);
    #pragma unroll
    for (int off = 32; off; off >>= 1) s += __shfl_xor(s, off);
    if (lane == 0) { g_stats[32768 + bj] = mx; g_stats[40960 + bj] = s; }
}

// ---------------- K2a: X -> transposed bf16 g_Xt[b][q][p][c][j] ----------------
__global__ void k_xt(const float* __restrict__ Xr, const float* __restrict__ Xi) {
    int b = blockIdx.x >> 4, q = blockIdx.x & 15;
    __shared__ float xs[2][64][65];
    int tid = threadIdx.x;
    #pragma unroll 4
    for (int rep = 0; rep < 32; ++rep) {
        int idx = rep * 256 + tid;                  // 8192
        int p = idx >> 12, j = (idx >> 6) & 63, c = idx & 63;
        const float* src = p ? Xi : Xr;
        xs[p][j][c] = src[((size_t)b * BN + q * 64 + j) * 64 + c];
    }
    __syncthreads();
    #pragma unroll
    for (int rep = 0; rep < 4; ++rep) {
        int idx = rep * 256 + tid;                  // 1024 uint4
        int p = idx >> 9, c = (idx >> 3) & 63, j8 = idx & 7;
        union { u16 h[8]; uint4 v; } pk;
        #pragma unroll
        for (int jj = 0; jj < 8; ++jj) pk.h[jj] = f2bf(xs[p][j8 * 8 + jj][c]);
        *(uint4*)&g_Xt[(size_t)(((b * 16 + q) * 2 + p) * 64 + c) * 64 + j8 * 8] = pk.v;
    }
}

// ---------------- K2b: w -> bf16 hi/lo planes g_wt[plane][o][kc] ----------------
__global__ void k_wt(const float* __restrict__ wr, const float* __restrict__ wi) {
    int t = blockIdx.x * 256 + threadIdx.x;         // 0..12287 ; w[k][c][o], t = kc*64+o
    int o = t & 63, kc = t >> 6;
    float vr = wr[t], vi = wi[t];
    u16 rh = f2bf(vr);
    u16 rl = f2bf(vr - bf2f(rh));
    u16 ih = f2bf(vi);
    u16 il = f2bf(vi - bf2f(ih));
    g_wt[(0 * 64 + o) * 192 + kc] = rh;
    g_wt[(1 * 64 + o) * 192 + kc] = rl;
    g_wt[(2 * 64 + o) * 192 + kc] = ih;
    g_wt[(3 * 64 + o) * 192 + kc] = il;
    g_wt[(4 * 64 + o) * 192 + kc] = (u16)(ih ^ 0x8000u);
    g_wt[(5 * 64 + o) * 192 + kc] = (u16)(il ^ 0x8000u);
}

// ---------------- K3: main kernel — async-DMA L staging, counted vmcnt ----------------
// grid 1024 = b(8) x it(64) x jh(2); 256 thr = 4 waves; 8 q-slices per block.
// L tile (24 KB) staged by 24 global_load_lds (6/wave), double-buffered; raw barriers.
// Lbuf layout: word(k,rc,row,j) = (k*8+rc*4+(row>>2))*256 + (row&3)*64 + j.
__global__ __launch_bounds__(256) void k_main(
    const float* __restrict__ Lr, const float* __restrict__ Li,
    const float* __restrict__ pbr, const float* __restrict__ pbi,
    const float* __restrict__ par, const float* __restrict__ pai) {
    __shared__ __align__(16) float Lbuf[2][6144];   // 48 KB
    __shared__ __align__(16) u16 lmS[6912];         // [k3][rc2][16][72]
    __shared__ __align__(16) float stS[4][512];     // 8 KB
    __shared__ __align__(16) float sA[2][16];

    int tid = threadIdx.x, w = tid >> 6, lane = tid & 63;
    int jh = blockIdx.x & 1, it = (blockIdx.x >> 1) & 63, b = blockIdx.x >> 7;
    int i0 = it * 16;
    int arow = lane & 15, kb = (lane >> 4) * 8;
    int ti = tid >> 4, tj4 = tid & 15;

    // ---- stage stats (plain __syncthreads: pre-loop vmcnt drain is harmless) ----
    {
        int jg = b * BN + jh * 512 + tid;
        stS[0][tid] = g_stats[16384 + jg];
        stS[1][tid] = g_stats[24576 + jg];
        stS[2][tid] = g_stats[32768 + jg];
        stS[3][tid] = g_stats[40960 + jg];
        stS[0][tid + 256] = g_stats[16384 + jg + 256];
        stS[1][tid + 256] = g_stats[24576 + jg + 256];
        stS[2][tid + 256] = g_stats[32768 + jg + 256];
        stS[3][tid + 256] = g_stats[40960 + jg + 256];
        if (tid < 32) {
            int p = tid >> 4, i = tid & 15;
            sA[p][i] = g_stats[p * 8192 + b * BN + i0 + i];
        }
    }
    __syncthreads();

    float brv = pbr[0], biv = pbi[0], alrv = par[0], aliv = pai[0];
    float sirv = sA[0][ti], siiv = sA[1][ti];

    f32x4 zz = {0.f, 0.f, 0.f, 0.f};
    f32x4 accr[3], acci[3];
    #pragma unroll
    for (int k = 0; k < 3; ++k) { accr[k] = zz; acci[k] = zz; }

    auto stageL = [&](int q, int buf) {
        #pragma unroll
        for (int t = 0; t < 6; ++t) {
            int l = w * 6 + t;
            int k = l >> 3, rc = (l >> 2) & 1, rg = l & 3;
            int row = rg * 4 + (lane >> 4), j = (lane & 15) * 4;
            const float* src = rc ? Li : Lr;
            const float* g = src + ((size_t)(b * 3 + k) * BN + (i0 + row)) * BN
                                 + jh * 512 + q * 64 + j;
            gl_lds16(g, &Lbuf[buf][l * 256]);
        }
    };

    // prologue: stage slice 0 into buf 0   [outstanding: 6]
    stageL(0, 0);

    #pragma unroll
    for (int qi = 0; qi < 8; ++qi) {
        int q = jh * 8 + qi;
        int cur = qi & 1;
        // a. Bx loads (issued BEFORE prefetch => compiler waits them with vmcnt(6))
        bf16x8 Bxr[2], Bxi_[2];
        {
            size_t xb = (size_t)((b * 16 + q) * 2) * 4096 + (size_t)(w * 16 + arow) * 64 + kb;
            #pragma unroll
            for (int ks = 0; ks < 2; ++ks) {
                Bxr[ks]  = *(const bf16x8*)&g_Xt[xb + ks * 32];
                Bxi_[ks] = *(const bf16x8*)&g_Xt[xb + 4096 + ks * 32];
            }
        }
        // b. prefetch next slice
        if (qi < 7) stageL(qi + 1, cur ^ 1);
        // c. attention for this thread's 4 j's
        float arj[4], aij[4];
        {
            int jloc = qi * 64 + tj4 * 4;
            #pragma unroll
            for (int e = 0; e < 4; ++e) {
                float sr = sirv + stS[0][jloc + e] + brv;
                float si = siiv + stS[1][jloc + e] + biv;
                sr = sr >= 0.f ? sr : alrv * sr;
                si = si >= 0.f ? si : aliv * si;
                float mg = sqrtf(sr * sr + si * si);
                float sc = __expf(mg - stS[2][jloc + e]) / (stS[3][jloc + e] * fmaxf(mg, 1e-12f));
                arj[e] = sc * sr;
                aij[e] = sc * si;
            }
        }
        // d. wait current L tile landed (leave Bx + next-prefetch in flight), sync
        if (qi < 7) { asm volatile("s_waitcnt vmcnt(10)" ::: "memory"); }
        else        { asm volatile("s_waitcnt vmcnt(4)"  ::: "memory"); }
        __builtin_amdgcn_s_barrier();
        __builtin_amdgcn_sched_barrier(0);
        // f. modulate from Lbuf[cur] -> lmS
        #pragma unroll
        for (int k = 0; k < 3; ++k) {
            int base = (k * 8 + (ti >> 2)) * 256 + (ti & 3) * 64 + tj4 * 4;
            float4 r4 = *(const float4*)&Lbuf[cur][base];
            float4 s4 = *(const float4*)&Lbuf[cur][base + 1024];
            float lr4[4] = {r4.x, r4.y, r4.z, r4.w};
            float li4[4] = {s4.x, s4.y, s4.z, s4.w};
            union { u16 h[4]; uint2 v; } pr, pi;
            #pragma unroll
            for (int e = 0; e < 4; ++e) {
                float mr = lr4[e] * arj[e] - li4[e] * aij[e];
                float mi = lr4[e] * aij[e] + li4[e] * arj[e];
                pr.h[e] = f2bf(mr);
                pi.h[e] = f2bf(mi);
            }
            *(uint2*)(lmS + ((k * 2 + 0) * 16 + ti) * 72 + tj4 * 4) = pr.v;
            *(uint2*)(lmS + ((k * 2 + 1) * 16 + ti) * 72 + tj4 * 4) = pi.v;
        }
        asm volatile("s_waitcnt lgkmcnt(0)" ::: "memory");
        __builtin_amdgcn_s_barrier();
        __builtin_amdgcn_sched_barrier(0);
        // g. MFMA: wave owns c-quarter w, loops k (Bx waited by compiler: vmcnt(6))
        #pragma unroll
        for (int k = 0; k < 3; ++k) {
            #pragma unroll
            for (int ks = 0; ks < 2; ++ks) {
                int kc = ks * 32 + kb;
                bf16x8 aR = *(const bf16x8*)(lmS + ((k * 2 + 0) * 16 + arow) * 72 + kc);
                bf16x8 aI = *(const bf16x8*)(lmS + ((k * 2 + 1) * 16 + arow) * 72 + kc);
                bf16x8 aIn;
                #pragma unroll
                for (int z = 0; z < 8; ++z) aIn[z] = (short)(aI[z] ^ (short)0x8000);
                accr[k] = __builtin_amdgcn_mfma_f32_16x16x32_bf16(aR,  Bxr[ks],  accr[k], 0, 0, 0);
                acci[k] = __builtin_amdgcn_mfma_f32_16x16x32_bf16(aR,  Bxi_[ks], acci[k], 0, 0, 0);
                acci[k] = __builtin_amdgcn_mfma_f32_16x16x32_bf16(aI,  Bxr[ks],  acci[k], 0, 0, 0);
                #pragma unroll
                for (int z = 0; z < 8; ++z) aIn[z] = (short)(aIn[z]);
                accr[k] = __builtin_amdgcn_mfma_f32_16x16x32_bf16(aIn, Bxi_[ks], accr[k], 0, 0, 0);
            }
        }
        asm volatile("s_waitcnt lgkmcnt(0)" ::: "memory");
        __builtin_amdgcn_s_barrier();
    }

    // ---- write partial LX (f32): kc = k*64 + w*16 + arow ----
    {
        size_t base = (size_t)blockIdx.x * 6144;
        #pragma unroll
        for (int k = 0; k < 3; ++k) {
            int kc = k * 64 + w * 16 + arow;
            #pragma unroll
            for (int p = 0; p < 2; ++p) {
                f32x4 fr = p ? acci[k] : accr[k];
                #pragma unroll
                for (int r = 0; r < 4; ++r) {
                    int row = (lane >> 4) * 4 + r;
                    g_part[base + (size_t)(p * 16 + row) * 192 + kc] = fr[r];
                }
            }
        }
    }
}

// ---------------- K4: combine 2 partials + stage 2 -> out ----------------
__global__ __launch_bounds__(256) void k_out(float* __restrict__ out) {
    __shared__ __align__(16) u16 LXs[12800];   // [plane4][16][200], kc in [0,192)
    int tid = threadIdx.x, wid = tid >> 6, lane = tid & 63;
    int b = blockIdx.x >> 6, it = blockIdx.x & 63, i0 = it * 16;
    size_t p0 = (size_t)((b * 64 + it) * 2 + 0) * 6144;
    size_t p1 = p0 + 6144;

    #pragma unroll
    for (int rep = 0; rep < 6; ++rep) {
        int idx = rep * 256 + tid;                // 1536 float4
        float4 a = *(const float4*)&g_part[p0 + (size_t)idx * 4];
        float4 c = *(const float4*)&g_part[p1 + (size_t)idx * 4];
        float s[4] = {a.x + c.x, a.y + c.y, a.z + c.z, a.w + c.w};
        int f0 = idx * 4;
        int rc = f0 / 3072, rem = f0 - rc * 3072;
        int row = rem / 192, kc = rem - row * 192;
        #pragma unroll
        for (int t = 0; t < 4; ++t) {
            float v = s[t];
            u16 hi = f2bf(v);
            u16 lo = f2bf(v - bf2f(hi));
            LXs[((rc * 2 + 0) * 16 + row) * 200 + kc + t] = hi;
            LXs[((rc * 2 + 1) * 16 + row) * 200 + kc + t] = lo;
        }
    }
    __syncthreads();

    f32x4 zz = {0.f, 0.f, 0.f, 0.f};
    f32x4 o_r = zz, o_i = zz;
    int arow = lane & 15, kb = (lane >> 4) * 8;
    int o = wid * 16 + arow;
    #pragma unroll
    for (int ks = 0; ks < 6; ++ks) {
        int kc = ks * 32 + kb;
        bf16x8 Arh = *(const bf16x8*)(LXs + (0 * 16 + arow) * 200 + kc);
        bf16x8 Arl = *(const bf16x8*)(LXs + (1 * 16 + arow) * 200 + kc);
        bf16x8 Aih = *(const bf16x8*)(LXs + (2 * 16 + arow) * 200 + kc);
        bf16x8 Ail = *(const bf16x8*)(LXs + (3 * 16 + arow) * 200 + kc);
        bf16x8 Wrh  = *(const bf16x8*)&g_wt[(0 * 64 + o) * 192 + kc];
        bf16x8 Wrl  = *(const bf16x8*)&g_wt[(1 * 64 + o) * 192 + kc];
        bf16x8 Wih  = *(const bf16x8*)&g_wt[(2 * 64 + o) * 192 + kc];
        bf16x8 Wil  = *(const bf16x8*)&g_wt[(3 * 64 + o) * 192 + kc];
        bf16x8 Wihn = *(const bf16x8*)&g_wt[(4 * 64 + o) * 192 + kc];
        bf16x8 Wiln = *(const bf16x8*)&g_wt[(5 * 64 + o) * 192 + kc];
        o_r = __builtin_amdgcn_mfma_f32_16x16x32_bf16(Arh, Wrh,  o_r, 0, 0, 0);
        o_r = __builtin_amdgcn_mfma_f32_16x16x32_bf16(Arh, Wrl,  o_r, 0, 0, 0);
        o_r = __builtin_amdgcn_mfma_f32_16x16x32_bf16(Arl, Wrh,  o_r, 0, 0, 0);
        o_r = __builtin_amdgcn_mfma_f32_16x16x32_bf16(Aih, Wihn, o_r, 0, 0, 0);
        o_r = __builtin_amdgcn_mfma_f32_16x16x32_bf16(Aih, Wiln, o_r, 0, 0, 0);
        o_r = __builtin_amdgcn_mfma_f32_16x16x32_bf16(Ail, Wihn, o_r, 0, 0, 0);
        o_i = __builtin_amdgcn_mfma_f32_16x16x32_bf16(Arh, Wih,  o_i, 0, 0, 0);
        o_i = __builtin_amdgcn_mfma_f32_16x16x32_bf16(Arh, Wil,  o_i, 0, 0, 0);
        o_i = __builtin_amdgcn_mfma_f32_16x16x32_bf16(Arl, Wih,  o_i, 0, 0, 0);
        o_i = __builtin_amdgcn_mfma_f32_16x16x32_bf16(Aih, Wrh,  o_i, 0, 0, 0);
        o_i = __builtin_amdgcn_mfma_f32_16x16x32_bf16(Aih, Wrl,  o_i, 0, 0, 0);
        o_i = __builtin_amdgcn_mfma_f32_16x16x32_bf16(Ail, Wrh,  o_i, 0, 0, 0);
    }
    #pragma unroll
    for (int r = 0; r < 4; ++r) {
        int i = (lane >> 4) * 4 + r;
        size_t off = ((size_t)b * BN + i0 + i) * 64 + o;
        out[off] = o_r[r];
        out[524288 + off] = o_i[r];
    }
}

extern "C" void kernel_launch(void* const* d_in, const int* in_sizes, int n_in,
                              void* d_out, int out_size, void* d_ws, size_t ws_size,
                              hipStream_t stream) {
    const float* Xr  = (const float*)d_in[0];
    const float* Xi  = (const float*)d_in[1];
    const float* Lr  = (const float*)d_in[2];
    const float* Li  = (const float*)d_in[3];
    const float* asr = (const float*)d_in[4];
    const float* asi = (const float*)d_in[5];
    const float* adr = (const float*)d_in[6];
    const float* adi = (const float*)d_in[7];
    const float* pbr = (const float*)d_in[8];
    const float* pbi = (const float*)d_in[9];
    const float* par = (const float*)d_in[10];
    const float* pai = (const float*)d_in[11];
    const float* wr  = (const float*)d_in[12];
    const float* wi  = (const float*)d_in[13];
    float* out = (float*)d_out;

    k_sisj<<<2048, 256, 0, stream>>>(Xr, Xi, asr, asi, adr, adi);
    k_mz<<<2048, 256, 0, stream>>>(pbr, pbi, par, pai);
    k_xt<<<128, 256, 0, stream>>>(Xr, Xi);
    k_wt<<<48, 256, 0, stream>>>(wr, wi);
    k_main<<<1024, 256, 0, stream>>>(Lr, Li, pbr, pbi, par, pai);
    k_out<<<512, 256, 0, stream>>>(out);
}